// Round 10
// baseline (772.218 us; speedup 1.0000x reference)
//
#include <hip/hip_runtime.h>
#include <cstddef>
#include <cstdint>

// Problem constants
#define L_SEQ   2048
#define BATCH_N 4
#define DMODEL  512
#define DINNER  1024
#define DSTATE  8
#define KCONV   4
#define DTRANK  32
#define NBLK    3
#define NCLS_N  10
#define MROWS   (BATCH_N * L_SEQ)   // 8192
#define DBLW    48                  // dt_rank + 2*d_state
#define NSPLIT  8                   // x_proj split-K grid (8 -> 512 blocks, 2/CU)

// Chunked-scan parameters: LC2=16 rows/chunk -> 512 blocks (2/CU, 8 waves/CU)
#define LC2 16
#define NC2 (L_SEQ / LC2)   // 128
#define VD  4

typedef __attribute__((ext_vector_type(8))) short bf16x8;
typedef __attribute__((ext_vector_type(4))) short bf16x4;
typedef __attribute__((ext_vector_type(4))) float f32x4;

// Fast inline transcendentals (v_exp_f32 / v_log_f32 — no ocml calls).
__device__ __forceinline__ float sigmoid_fast(float x) { return 1.f / (1.f + __expf(-x)); }
__device__ __forceinline__ float silu_fast(float x)    { return x * sigmoid_fast(x); }
__device__ __forceinline__ float softplus_fast(float x){
    return fmaxf(x, 0.f) + __logf(1.f + __expf(-fabsf(x)));
}

__device__ __forceinline__ unsigned short f2bf(float f) {
    union { float f; uint32_t u; } v; v.f = f;
    const uint32_t u = v.u;
    return (unsigned short)((u + 0x7fffu + ((u >> 16) & 1u)) >> 16);  // RNE
}
__device__ __forceinline__ float bf2f(unsigned short h) {
    union { uint32_t u; float f; } v; v.u = ((uint32_t)h) << 16;
    return v.f;
}
__device__ __forceinline__ float bf2f_s(short h) { return bf2f((unsigned short)h); }

// async global -> LDS, 16 bytes per lane
__device__ __forceinline__ void load_lds16(const void* g, void* l) {
    __builtin_amdgcn_global_load_lds(
        (const __attribute__((address_space(1))) unsigned int*)g,
        (__attribute__((address_space(3))) unsigned int*)l,
        16, 0, 0);
}

// ---------------------------------------------------------------------------
// bf16 MFMA GEMM: acc = A[M,K] @ Bt[N,K]^T, 128 x NT tile, BK=64, 256 thr.
// Single-buffered staging; XOR-swizzled LDS; LDS-bounced coalesced epilogue.
//   NT = 128: 4 waves 2x2, wave = 64x64
//   NT =  64: wave = 64x32 — 2x blocks for concurrency-starved shapes
//   EPI = 0: Obf = bf16(acc)
//   EPI = 2: v = acc + Xres; Xres = v (fp32); Obf = bf16(v)
// ---------------------------------------------------------------------------
template <int K, int NT, int EPI>
__global__ __launch_bounds__(256) void gemm_bf16(
    const unsigned short* __restrict__ A, int lda,
    const unsigned short* __restrict__ Bt, int ldb,
    int ldc,
    unsigned short* __restrict__ Obf,
    float* __restrict__ Xres)
{
    constexpr int BCH   = NT / 8;
    constexpr int NTW   = NT / 32;
    constexpr int STAGE = 8192 + NT * 64;
    constexpr int EPIL  = 128 * (NT + 8);
    constexpr int SMEM  = (STAGE > EPIL) ? STAGE : EPIL;
    __shared__ unsigned short sMem[SMEM];
    unsigned short* sA = sMem;
    unsigned short* sB = sMem + 8192;

    const int tid  = threadIdx.x;
    const int lane = tid & 63;
    const int wave = tid >> 6;
    const int m0 = blockIdx.y * 128;
    const int n0 = blockIdx.x * NT;
    const int wm = (wave >> 1) * 64;
    const int wn = (wave & 1) * (NT / 2);
    const int lm = lane & 15;
    const int lq = lane >> 4;

    const int srow = lane >> 3;
    const int scol = ((lane & 7) ^ srow) * 8;

    f32x4 acc[4][NTW];
    #pragma unroll
    for (int i = 0; i < 4; ++i)
        #pragma unroll
        for (int j = 0; j < NTW; ++j) acc[i][j] = (f32x4){0.f, 0.f, 0.f, 0.f};

    for (int k0 = 0; k0 < K; k0 += 64) {
        #pragma unroll
        for (int c = wave; c < 16; c += 4)
            load_lds16(A + (size_t)(m0 + c * 8 + srow) * lda + k0 + scol, &sA[c * 512]);
        #pragma unroll
        for (int c = wave; c < BCH; c += 4)
            load_lds16(Bt + (size_t)(n0 + c * 8 + srow) * ldb + k0 + scol, &sB[c * 512]);
        __syncthreads();
        #pragma unroll
        for (int ks = 0; ks < 2; ++ks) {
            bf16x8 aF[4], bF[NTW];
            #pragma unroll
            for (int mt = 0; mt < 4; ++mt) {
                const int row = wm + mt * 16 + lm;
                aF[mt] = *(const bf16x8*)&sA[row * 64 + (((ks * 4 + lq) ^ (lm & 7)) * 8)];
            }
            #pragma unroll
            for (int nt = 0; nt < NTW; ++nt) {
                const int row = wn + nt * 16 + lm;
                bF[nt] = *(const bf16x8*)&sB[row * 64 + (((ks * 4 + lq) ^ (lm & 7)) * 8)];
            }
            #pragma unroll
            for (int mt = 0; mt < 4; ++mt)
                #pragma unroll
                for (int nt = 0; nt < NTW; ++nt)
                    acc[mt][nt] = __builtin_amdgcn_mfma_f32_16x16x32_bf16(
                        aF[mt], bF[nt], acc[mt][nt], 0, 0, 0);
        }
        __syncthreads();
    }

    unsigned short* sOut = sMem;
    #pragma unroll
    for (int mt = 0; mt < 4; ++mt) {
        #pragma unroll
        for (int nt = 0; nt < NTW; ++nt) {
            #pragma unroll
            for (int r = 0; r < 4; ++r) {
                const int row = wm + mt * 16 + lq * 4 + r;
                const int col = wn + nt * 16 + lm;
                float v = acc[mt][nt][r];
                if (EPI == 2) {
                    const size_t gi = (size_t)(m0 + row) * ldc + n0 + col;
                    v += Xres[gi];
                    Xres[gi] = v;
                }
                sOut[row * (NT + 8) + col] = f2bf(v);
            }
        }
    }
    __syncthreads();
    #pragma unroll
    for (int j = 0; j < NT / 16; ++j) {
        const int idx = j * 256 + tid;
        const int row = idx / (NT / 8);
        const int cpos = (idx % (NT / 8)) * 8;
        *(bf16x8*)&Obf[(size_t)(m0 + row) * ldc + n0 + cpos] =
            *(const bf16x8*)&sOut[row * (NT + 8) + cpos];
    }
}

// ---------------------------------------------------------------------------
// x_proj: dblsum[M,48] += ub[M,1024] @ Wxt[48,1024]^T, split-K grid, atomics.
// NSPLIT=8 -> 512 blocks (2/CU, 8 waves/CU) for latency hiding.
// ---------------------------------------------------------------------------
__global__ __launch_bounds__(256) void gemm_xproj(
    const unsigned short* __restrict__ ub,
    const unsigned short* __restrict__ Wxt,
    float* __restrict__ dblsum)
{
    const int tid = threadIdx.x, lane = tid & 63, wave = tid >> 6;
    const int lm = lane & 15, lq = lane >> 4;
    const int rowA = blockIdx.x * 128 + wave * 32;
    const int split = blockIdx.y;
    const int k0 = split * (DINNER / NSPLIT);

    f32x4 acc[2][3];
    #pragma unroll
    for (int i = 0; i < 2; ++i)
        #pragma unroll
        for (int j = 0; j < 3; ++j) acc[i][j] = (f32x4){0.f, 0.f, 0.f, 0.f};

    #pragma unroll
    for (int kk = 0; kk < DINNER / NSPLIT; kk += 32) {
        const int k = k0 + kk;
        bf16x8 aF[2], bF[3];
        #pragma unroll
        for (int mt = 0; mt < 2; ++mt)
            aF[mt] = *(const bf16x8*)&ub[(size_t)(rowA + mt * 16 + lm) * DINNER + k + lq * 8];
        #pragma unroll
        for (int nt = 0; nt < 3; ++nt)
            bF[nt] = *(const bf16x8*)&Wxt[(size_t)(nt * 16 + lm) * DINNER + k + lq * 8];
        #pragma unroll
        for (int mt = 0; mt < 2; ++mt)
            #pragma unroll
            for (int nt = 0; nt < 3; ++nt)
                acc[mt][nt] = __builtin_amdgcn_mfma_f32_16x16x32_bf16(
                    aF[mt], bF[nt], acc[mt][nt], 0, 0, 0);
    }
    #pragma unroll
    for (int mt = 0; mt < 2; ++mt)
        #pragma unroll
        for (int nt = 0; nt < 3; ++nt)
            #pragma unroll
            for (int r = 0; r < 4; ++r)
                atomicAdd(&dblsum[(size_t)(rowA + mt * 16 + lq * 4 + r) * DBLW
                                  + nt * 16 + lm], acc[mt][nt][r]);
}

// ---------------------------------------------------------------------------
// dt_proj fused: delta = bf16(softplus(dblsum[:, :32] @ Wdtt^T + bdt))
// ---------------------------------------------------------------------------
__global__ __launch_bounds__(256) void gemm_dt(
    const float* __restrict__ dblsum,        // (M, 48)
    const unsigned short* __restrict__ Wdtt, // (1024, 32) bf16
    const float* __restrict__ bdt,           // (1024,)
    unsigned short* __restrict__ delta_bf)   // (M, 1024)
{
    const int lane = threadIdx.x & 63;
    const int wave = threadIdx.x >> 6;
    const int lm = lane & 15, lq = lane >> 4;
    const int m0 = blockIdx.y * 64;
    const int colbase = blockIdx.x * 256;
    const int mrow = m0 + wave * 16;

    __shared__ unsigned short sOut[64 * 264];

    const float* p = &dblsum[(size_t)(mrow + lm) * DBLW + lq * 8];
    float4 x0 = *(const float4*)p;
    float4 x1 = *(const float4*)(p + 4);
    bf16x8 aF;
    aF[0] = (short)f2bf(x0.x); aF[1] = (short)f2bf(x0.y);
    aF[2] = (short)f2bf(x0.z); aF[3] = (short)f2bf(x0.w);
    aF[4] = (short)f2bf(x1.x); aF[5] = (short)f2bf(x1.y);
    aF[6] = (short)f2bf(x1.z); aF[7] = (short)f2bf(x1.w);

    #pragma unroll
    for (int nt = 0; nt < 16; ++nt) {
        const int col16 = colbase + nt * 16;
        bf16x8 bF = *(const bf16x8*)&Wdtt[(size_t)(col16 + lm) * DTRANK + lq * 8];
        f32x4 acc = (f32x4){0.f, 0.f, 0.f, 0.f};
        acc = __builtin_amdgcn_mfma_f32_16x16x32_bf16(aF, bF, acc, 0, 0, 0);
        const float bias = bdt[col16 + lm];
        #pragma unroll
        for (int r = 0; r < 4; ++r)
            sOut[(wave * 16 + lq * 4 + r) * 264 + (nt * 16 + lm)] =
                f2bf(softplus_fast(acc[r] + bias));
    }
    __syncthreads();
    #pragma unroll
    for (int j = 0; j < 8; ++j) {
        const int idx = j * 256 + threadIdx.x;
        const int row = idx >> 5;
        const int cpos = (idx & 31) * 8;
        *(bf16x8*)&delta_bf[(size_t)(m0 + row) * DINNER + colbase + cpos] =
            *(const bf16x8*)&sOut[row * 264 + cpos];
    }
}

// ---------------------------------------------------------------------------
// Weight transpose + cast: out[n][k] bf16 = in[k][n] fp32
// ---------------------------------------------------------------------------
__global__ __launch_bounds__(256) void transpose_cast(
    const float* __restrict__ in, unsigned short* __restrict__ out,
    int Kdim, int Ndim, size_t in_stride, size_t out_stride)
{
    __shared__ float s[32][33];
    const float* ip = in + blockIdx.z * in_stride;
    unsigned short* op = out + blockIdx.z * out_stride;
    const int bx = blockIdx.x * 32;
    const int by = blockIdx.y * 32;
    const int t = threadIdx.x;
    const int r = t >> 3;
    const int c4 = (t & 7) * 4;

    const int row = by + r;
    if (bx + c4 + 3 < Ndim) {
        float4 v = *(const float4*)&ip[(size_t)row * Ndim + bx + c4];
        s[r][c4 + 0] = v.x; s[r][c4 + 1] = v.y; s[r][c4 + 2] = v.z; s[r][c4 + 3] = v.w;
    } else {
        for (int i = 0; i < 4; ++i) {
            const int col = bx + c4 + i;
            s[r][c4 + i] = (col < Ndim) ? ip[(size_t)row * Ndim + col] : 0.f;
        }
    }
    __syncthreads();
    if (bx + r < Ndim) {
        unsigned short w0 = f2bf(s[c4 + 0][r]), w1 = f2bf(s[c4 + 1][r]);
        unsigned short w2 = f2bf(s[c4 + 2][r]), w3 = f2bf(s[c4 + 3][r]);
        uint2 pk;
        pk.x = (uint32_t)w0 | ((uint32_t)w1 << 16);
        pk.y = (uint32_t)w2 | ((uint32_t)w3 << 16);
        *(uint2*)&op[(size_t)(bx + r) * Kdim + by + c4] = pk;
    }
}

// fused: x_buf = x_in (fp32 copy) and xb = bf16(x_in)
__global__ void copy_cast(const float* __restrict__ in, float* __restrict__ cpy,
                          unsigned short* __restrict__ outb, int n4) {
    const int i = blockIdx.x * 256 + threadIdx.x;
    if (i >= n4) return;
    float4 v = ((const float4*)in)[i];
    ((float4*)cpy)[i] = v;
    uint2 pk;
    pk.x = (uint32_t)f2bf(v.x) | ((uint32_t)f2bf(v.y) << 16);
    pk.y = (uint32_t)f2bf(v.z) | ((uint32_t)f2bf(v.w) << 16);
    ((uint2*)outb)[i] = pk;
}

// conv weight transpose: cwt[blk][k][d] = cw[blk][d][k]
__global__ void conv_w_transpose(const float* __restrict__ cw, float* __restrict__ cwt) {
    const int i = blockIdx.x * 256 + threadIdx.x;
    if (i >= NBLK * DINNER * KCONV) return;
    const int blk = i >> 12;
    const int rem = i & 4095;
    const int d = rem >> 2;
    const int k = rem & 3;
    cwt[blk * 4096 + k * DINNER + d] = cw[blk * 4096 + d * KCONV + k];
}

// ---------------------------------------------------------------------------
// Depthwise causal conv (K=4) + bias + SiLU; 8 d per thread, bf16x8 I/O.
// Also zeroes dblsum (stream-ordered before gemm_xproj's atomics).
// ---------------------------------------------------------------------------
__global__ __launch_bounds__(256) void conv_silu_kernel(
    const unsigned short* __restrict__ xz,
    const float* __restrict__ cwt,   // (4, 1024)
    const float* __restrict__ cb,
    unsigned short* __restrict__ ub,
    float* __restrict__ dblsum)
{
    const int idx = blockIdx.x * 256 + threadIdx.x;   // over MROWS*128
    if (idx < MROWS * DBLW / 4)
        ((f32x4*)dblsum)[idx] = (f32x4){0.f, 0.f, 0.f, 0.f};

    const int dv = idx & 127;
    const int m  = idx >> 7;
    const int t  = m & (L_SEQ - 1);
    const int d0 = dv * 8;

    float acc[8];
    {
        float4 c0 = *(const float4*)&cb[d0];
        float4 c1 = *(const float4*)&cb[d0 + 4];
        acc[0] = c0.x; acc[1] = c0.y; acc[2] = c0.z; acc[3] = c0.w;
        acc[4] = c1.x; acc[5] = c1.y; acc[6] = c1.z; acc[7] = c1.w;
    }
    #pragma unroll
    for (int k = 0; k < KCONV; ++k) {
        const int tt = t + k - (KCONV - 1);
        if (tt >= 0) {
            bf16x8 xv = *(const bf16x8*)&xz[(size_t)(m - t + tt) * (2 * DINNER) + d0];
            float4 w0 = *(const float4*)&cwt[k * DINNER + d0];
            float4 w1 = *(const float4*)&cwt[k * DINNER + d0 + 4];
            acc[0] = fmaf(bf2f_s(xv[0]), w0.x, acc[0]);
            acc[1] = fmaf(bf2f_s(xv[1]), w0.y, acc[1]);
            acc[2] = fmaf(bf2f_s(xv[2]), w0.z, acc[2]);
            acc[3] = fmaf(bf2f_s(xv[3]), w0.w, acc[3]);
            acc[4] = fmaf(bf2f_s(xv[4]), w1.x, acc[4]);
            acc[5] = fmaf(bf2f_s(xv[5]), w1.y, acc[5]);
            acc[6] = fmaf(bf2f_s(xv[6]), w1.z, acc[6]);
            acc[7] = fmaf(bf2f_s(xv[7]), w1.w, acc[7]);
        }
    }
    bf16x8 o;
    #pragma unroll
    for (int j = 0; j < 8; ++j) o[j] = (short)f2bf(silu_fast(acc[j]));
    *(bf16x8*)&ub[(size_t)m * DINNER + d0] = o;
}

// ---------------------------------------------------------------------------
// 3-phase chunked selective scan; VD=4 channels/thread, LC2=16 rows/chunk.
// Grid (NC2=128, 4) = 512 blocks -> 2 blocks/CU, 8 waves/CU.
// ---------------------------------------------------------------------------
__global__ __launch_bounds__(256) void scan_chunk_kernel(
    const unsigned short* __restrict__ delta_bf,
    const unsigned short* __restrict__ ub,
    const float* __restrict__ dblsum,
    const float* __restrict__ A_log,
    float* __restrict__ Pbuf,
    float* __restrict__ Sbuf)
{
    const int c = blockIdx.x;
    const int b = blockIdx.y;
    const int tid = threadIdx.x;
    const int d0 = tid * VD;

    __shared__ float sB[LC2][DSTATE];

    const size_t m0 = (size_t)b * L_SEQ + c * LC2;
    if (tid < LC2 * DSTATE) {
        const int r = tid >> 3, n = tid & 7;
        sB[r][n] = dblsum[(m0 + r) * DBLW + DTRANK + n];
    }
    __syncthreads();

    float a[DSTATE * VD], P[DSTATE * VD], S[DSTATE * VD];
    #pragma unroll
    for (int n = 0; n < DSTATE; ++n)
        #pragma unroll
        for (int v = 0; v < VD; ++v) {
            a[n * VD + v] = -__expf(A_log[(d0 + v) * DSTATE + n]);
            P[n * VD + v] = 1.f;
            S[n * VD + v] = 0.f;
        }

    for (int r = 0; r < LC2; ++r) {
        const size_t m = m0 + r;
        bf16x4 dv = *(const bf16x4*)&delta_bf[m * DINNER + d0];
        bf16x4 uv = *(const bf16x4*)&ub[m * DINNER + d0];
        float dt[VD], du[VD];
        #pragma unroll
        for (int v = 0; v < VD; ++v) {
            dt[v] = bf2f_s(dv[v]);
            du[v] = dt[v] * bf2f_s(uv[v]);
        }
        #pragma unroll
        for (int n = 0; n < DSTATE; ++n) {
            const float bn = sB[r][n];
            #pragma unroll
            for (int v = 0; v < VD; ++v) {
                const float e = __expf(dt[v] * a[n * VD + v]);
                S[n * VD + v] = fmaf(e, S[n * VD + v], du[v] * bn);
                P[n * VD + v] *= e;
            }
        }
    }

    const size_t base = ((size_t)(b * NC2 + c) * DSTATE) * DINNER + d0;
    #pragma unroll
    for (int n = 0; n < DSTATE; ++n) {
        *(float4*)&Pbuf[base + (size_t)n * DINNER] = *(float4*)&P[n * VD];
        *(float4*)&Sbuf[base + (size_t)n * DINNER] = *(float4*)&S[n * VD];
    }
}

__global__ __launch_bounds__(256) void scan_combine_kernel(
    float* __restrict__ Pbuf,
    const float* __restrict__ Sbuf)
{
    const int g = blockIdx.x * 256 + threadIdx.x;
    const int b = g >> 10;
    const int d = g & (DINNER - 1);

    float h[DSTATE];
    #pragma unroll
    for (int n = 0; n < DSTATE; ++n) h[n] = 0.f;

    for (int c = 0; c < NC2; ++c) {
        const size_t base = ((size_t)(b * NC2 + c) * DSTATE) * DINNER + d;
        #pragma unroll
        for (int n = 0; n < DSTATE; ++n) {
            const size_t idx = base + (size_t)n * DINNER;
            const float p = Pbuf[idx];
            const float s = Sbuf[idx];
            Pbuf[idx] = h[n];
            h[n] = fmaf(p, h[n], s);
        }
    }
}

__global__ __launch_bounds__(256) void scan_out_kernel(
    const unsigned short* __restrict__ delta_bf,
    const unsigned short* __restrict__ ub,
    const float* __restrict__ dblsum,
    const unsigned short* __restrict__ xz,   // z at [., 1024+d]
    const float* __restrict__ A_log,
    const float* __restrict__ Dp,
    const float* __restrict__ Hin,
    unsigned short* __restrict__ ybuf)
{
    const int c = blockIdx.x;
    const int b = blockIdx.y;
    const int tid = threadIdx.x;
    const int d0 = tid * VD;

    __shared__ float sB[LC2][DSTATE];
    __shared__ float sC[LC2][DSTATE];

    const size_t m0 = (size_t)b * L_SEQ + c * LC2;
    if (tid < LC2 * 2 * DSTATE) {
        const int r = tid >> 4, j = tid & 15;
        const float v = dblsum[(m0 + r) * DBLW + DTRANK + j];
        if (j < DSTATE) sB[r][j] = v;
        else            sC[r][j - DSTATE] = v;
    }
    __syncthreads();

    float a[DSTATE * VD], h[DSTATE * VD];
    const size_t base = ((size_t)(b * NC2 + c) * DSTATE) * DINNER + d0;
    #pragma unroll
    for (int n = 0; n < DSTATE; ++n) {
        float4 hv = *(const float4*)&Hin[base + (size_t)n * DINNER];
        h[n * VD + 0] = hv.x; h[n * VD + 1] = hv.y;
        h[n * VD + 2] = hv.z; h[n * VD + 3] = hv.w;
        #pragma unroll
        for (int v = 0; v < VD; ++v)
            a[n * VD + v] = -__expf(A_log[(d0 + v) * DSTATE + n]);
    }
    float Dd[VD];
    {
        float4 dv4 = *(const float4*)&Dp[d0];
        Dd[0] = dv4.x; Dd[1] = dv4.y; Dd[2] = dv4.z; Dd[3] = dv4.w;
    }

    for (int r = 0; r < LC2; ++r) {
        const size_t m = m0 + r;
        bf16x4 dv = *(const bf16x4*)&delta_bf[m * DINNER + d0];
        bf16x4 uv = *(const bf16x4*)&ub[m * DINNER + d0];
        bf16x4 zv = *(const bf16x4*)&xz[m * (2 * DINNER) + DINNER + d0];
        float dt[VD], ut[VD], du[VD], acc[VD];
        #pragma unroll
        for (int v = 0; v < VD; ++v) {
            dt[v] = bf2f_s(dv[v]);
            ut[v] = bf2f_s(uv[v]);
            du[v] = dt[v] * ut[v];
            acc[v] = 0.f;
        }
        #pragma unroll
        for (int n = 0; n < DSTATE; ++n) {
            const float bn = sB[r][n];
            const float cn = sC[r][n];
            #pragma unroll
            for (int v = 0; v < VD; ++v) {
                const float e = __expf(dt[v] * a[n * VD + v]);
                h[n * VD + v] = fmaf(e, h[n * VD + v], du[v] * bn);
                acc[v] = fmaf(h[n * VD + v], cn, acc[v]);
            }
        }
        bf16x4 o;
        #pragma unroll
        for (int v = 0; v < VD; ++v)
            o[v] = (short)f2bf(fmaf(ut[v], Dd[v], acc[v]) * silu_fast(bf2f_s(zv[v])));
        *(bf16x4*)&ybuf[m * DINNER + d0] = o;
    }
}

// ---------------------------------------------------------------------------
#define POOL_SEGS 16
__global__ __launch_bounds__(512) void pool1_kernel(
    const float* __restrict__ x, float* __restrict__ part)
{
    const int b = blockIdx.y;
    const int seg = blockIdx.x;
    const int dm = threadIdx.x;
    const int tpseg = L_SEQ / POOL_SEGS;
    float s = 0.f;
    for (int t = seg * tpseg; t < (seg + 1) * tpseg; ++t)
        s += x[((size_t)b * L_SEQ + t) * DMODEL + dm];
    part[((size_t)b * POOL_SEGS + seg) * DMODEL + dm] = s;
}

// fused pool stage-2 + classifier: grid = BATCH_N, 512 threads
__global__ __launch_bounds__(512) void pool2_cls_kernel(
    const float* __restrict__ part,
    const float* __restrict__ w,     // (512, 10)
    const float* __restrict__ bias,  // (10,)
    float* __restrict__ out)
{
    __shared__ float sp[DMODEL];
    const int b = blockIdx.x;
    const int dm = threadIdx.x;
    float s = 0.f;
    #pragma unroll
    for (int seg = 0; seg < POOL_SEGS; ++seg)
        s += part[((size_t)b * POOL_SEGS + seg) * DMODEL + dm];
    sp[dm] = s * (1.f / (float)L_SEQ);
    __syncthreads();
    if (dm < NCLS_N) {
        float acc = bias[dm];
        for (int k = 0; k < DMODEL; ++k)
            acc = fmaf(sp[k], w[k * NCLS_N + dm], acc);
        out[b * NCLS_N + dm] = acc;
    }
}

// ---------------------------------------------------------------------------
extern "C" void kernel_launch(void* const* d_in, const int* in_sizes, int n_in,
                              void* d_out, int out_size, void* d_ws, size_t ws_size,
                              hipStream_t stream) {
    const float* x_in      = (const float*)d_in[0];
    const float* in_proj_w = (const float*)d_in[1];
    const float* conv_w    = (const float*)d_in[2];
    const float* conv_b    = (const float*)d_in[3];
    const float* x_proj_w  = (const float*)d_in[4];
    const float* dt_proj_w = (const float*)d_in[5];
    const float* dt_proj_b = (const float*)d_in[6];
    const float* A_log     = (const float*)d_in[7];
    const float* Dp        = (const float*)d_in[8];
    const float* out_proj_w= (const float*)d_in[9];
    const float* cls_w     = (const float*)d_in[10];
    const float* cls_b     = (const float*)d_in[11];
    float* out = (float*)d_out;

    // Workspace layout (bytes, 256-aligned)
    char* w = (char*)d_ws;
    auto alloc = [&](size_t bytes) { char* p = w; w += (bytes + 255) & ~(size_t)255; return p; };
    float*          x_buf  = (float*)         alloc((size_t)MROWS * DMODEL * 4);
    unsigned short* xz_bf  = (unsigned short*)alloc((size_t)MROWS * 2 * DINNER * 2);
    unsigned short* ub     = (unsigned short*)alloc((size_t)MROWS * DINNER * 2);
    unsigned short* delta  = (unsigned short*)alloc((size_t)MROWS * DINNER * 2);
    float*          dblsum = (float*)         alloc((size_t)MROWS * DBLW * 4);
    float*          Pbuf   = (float*)         alloc((size_t)BATCH_N * NC2 * DSTATE * DINNER * 4);
    float*          Sbuf   = (float*)         alloc((size_t)BATCH_N * NC2 * DSTATE * DINNER * 4);
    unsigned short* xb     = (unsigned short*)alloc((size_t)MROWS * DMODEL * 2);
    unsigned short* ybuf   = (unsigned short*)alloc((size_t)MROWS * DINNER * 2);
    unsigned short* Wit    = (unsigned short*)alloc((size_t)NBLK * 2048 * 512 * 2);
    unsigned short* Wot    = (unsigned short*)alloc((size_t)NBLK * 512 * 1024 * 2);
    unsigned short* Wxt    = (unsigned short*)alloc((size_t)NBLK * DBLW * 1024 * 2);
    unsigned short* Wdtt   = (unsigned short*)alloc((size_t)NBLK * 1024 * DTRANK * 2);
    float*          cwt    = (float*)         alloc((size_t)NBLK * KCONV * DINNER * 4);
    float*          part   = (float*)         alloc((size_t)BATCH_N * POOL_SEGS * DMODEL * 4);

    // Prep
    copy_cast<<<(MROWS * DMODEL / 4) / 256, 256, 0, stream>>>(
        x_in, x_buf, xb, MROWS * DMODEL / 4);
    transpose_cast<<<dim3(2048 / 32, 512 / 32, NBLK), 256, 0, stream>>>(
        in_proj_w, Wit, 512, 2048, (size_t)512 * 2048, (size_t)2048 * 512);
    transpose_cast<<<dim3(512 / 32, 1024 / 32, NBLK), 256, 0, stream>>>(
        out_proj_w, Wot, 1024, 512, (size_t)1024 * 512, (size_t)512 * 1024);
    transpose_cast<<<dim3(2, 1024 / 32, NBLK), 256, 0, stream>>>(
        x_proj_w, Wxt, 1024, DBLW, (size_t)1024 * DBLW, (size_t)DBLW * 1024);
    transpose_cast<<<dim3(1024 / 32, 1, NBLK), 256, 0, stream>>>(
        dt_proj_w, Wdtt, DTRANK, 1024, (size_t)DTRANK * 1024, (size_t)1024 * DTRANK);
    conv_w_transpose<<<(NBLK * DINNER * KCONV + 255) / 256, 256, 0, stream>>>(conv_w, cwt);

    for (int blk = 0; blk < NBLK; ++blk) {
        const unsigned short* Wit_b  = Wit  + (size_t)blk * 2048 * 512;
        const unsigned short* Wot_b  = Wot  + (size_t)blk * 512 * 1024;
        const unsigned short* Wxt_b  = Wxt  + (size_t)blk * DBLW * 1024;
        const unsigned short* Wdtt_b = Wdtt + (size_t)blk * 1024 * DTRANK;
        const float* cwt_b = cwt + (size_t)blk * KCONV * DINNER;
        const float* cb  = conv_b    + (size_t)blk * DINNER;
        const float* bdt = dt_proj_b + (size_t)blk * DINNER;
        const float* Al  = A_log     + (size_t)blk * DINNER * DSTATE;
        const float* Dv  = Dp        + (size_t)blk * DINNER;

        // 1) xz_bf = bf16(xb @ Wit^T)   K=512, 128x128 tiles
        gemm_bf16<512, 128, 0><<<dim3(2048 / 128, MROWS / 128), 256, 0, stream>>>(
            xb, DMODEL, Wit_b, DMODEL, 2 * DINNER, xz_bf, nullptr);
        // 2) ub = bf16(silu(conv(xz_bf lo) + cb)); zeroes dblsum
        conv_silu_kernel<<<(MROWS * 128) / 256, 256, 0, stream>>>(
            xz_bf, cwt_b, cb, ub, dblsum);
        // 3) dblsum += ub @ Wxt^T (split-K grid x8, atomics)
        gemm_xproj<<<dim3(MROWS / 128, NSPLIT), 256, 0, stream>>>(ub, Wxt_b, dblsum);
        // 4) delta = bf16(softplus(dblsum[:, :32] @ Wdtt^T + bdt))
        gemm_dt<<<dim3(DINNER / 256, MROWS / 64), 256, 0, stream>>>(
            dblsum, Wdtt_b, bdt, delta);
        // 5) chunked scan (LC2=16 -> 512 blocks, 2/CU)
        {
            dim3 gridA(NC2, BATCH_N);
            scan_chunk_kernel<<<gridA, 256, 0, stream>>>(delta, ub, dblsum, Al, Pbuf, Sbuf);
            scan_combine_kernel<<<(BATCH_N * DINNER) / 256, 256, 0, stream>>>(Pbuf, Sbuf);
            scan_out_kernel<<<gridA, 256, 0, stream>>>(delta, ub, dblsum, xz_bf, Al, Dv, Pbuf, ybuf);
        }
        // 6) x_buf += ybuf @ Wot^T; xb = bf16(x_buf)   K=1024, 128x64 tiles
        gemm_bf16<1024, 64, 2><<<dim3(DMODEL / 64, MROWS / 128), 256, 0, stream>>>(
            ybuf, DINNER, Wot_b, DINNER, DMODEL, xb, x_buf);
    }

    // mean pool + classifier
    {
        dim3 grid1(POOL_SEGS, BATCH_N);
        pool1_kernel<<<grid1, DMODEL, 0, stream>>>(x_buf, part);
        pool2_cls_kernel<<<BATCH_N, DMODEL, 0, stream>>>(part, cls_w, cls_b, out);
    }
}

// Round 11
// 654.662 us; speedup vs baseline: 1.1796x; 1.1796x over previous
//
#include <hip/hip_runtime.h>
#include <cstddef>
#include <cstdint>

// Problem constants
#define L_SEQ   2048
#define BATCH_N 4
#define DMODEL  512
#define DINNER  1024
#define DSTATE  8
#define KCONV   4
#define DTRANK  32
#define NBLK    3
#define NCLS_N  10
#define MROWS   (BATCH_N * L_SEQ)   // 8192
#define DBLW    48                  // dt_rank + 2*d_state
#define NSPLIT  8                   // x_proj split-K grid (8 -> 512 blocks, 2/CU)

// Chunked-scan parameters: LC2=16 rows/chunk -> 512 blocks (2/CU, 8 waves/CU)
#define LC2 16
#define NC2 (L_SEQ / LC2)   // 128
#define VD  4

typedef __attribute__((ext_vector_type(8))) short bf16x8;
typedef __attribute__((ext_vector_type(4))) short bf16x4;
typedef __attribute__((ext_vector_type(4))) float f32x4;

// Fast inline transcendentals (v_exp_f32 / v_log_f32 — no ocml calls).
__device__ __forceinline__ float sigmoid_fast(float x) { return 1.f / (1.f + __expf(-x)); }
__device__ __forceinline__ float silu_fast(float x)    { return x * sigmoid_fast(x); }
__device__ __forceinline__ float softplus_fast(float x){
    return fmaxf(x, 0.f) + __logf(1.f + __expf(-fabsf(x)));
}

__device__ __forceinline__ unsigned short f2bf(float f) {
    union { float f; uint32_t u; } v; v.f = f;
    const uint32_t u = v.u;
    return (unsigned short)((u + 0x7fffu + ((u >> 16) & 1u)) >> 16);  // RNE
}
__device__ __forceinline__ float bf2f(unsigned short h) {
    union { uint32_t u; float f; } v; v.u = ((uint32_t)h) << 16;
    return v.f;
}
__device__ __forceinline__ float bf2f_s(short h) { return bf2f((unsigned short)h); }

// async global -> LDS, 16 bytes per lane
__device__ __forceinline__ void load_lds16(const void* g, void* l) {
    __builtin_amdgcn_global_load_lds(
        (const __attribute__((address_space(1))) unsigned int*)g,
        (__attribute__((address_space(3))) unsigned int*)l,
        16, 0, 0);
}

// ---------------------------------------------------------------------------
// bf16 MFMA GEMM: acc = A[M,K] @ Bt[N,K]^T, 128 x NT tile, BK=64, 256 thr.
// Single-buffered staging; XOR-swizzled LDS; LDS-bounced coalesced epilogue.
//   NT = 128: 4 waves 2x2, wave = 64x64
//   NT =  64: wave = 64x32 — 2x blocks for concurrency-starved shapes
//   EPI = 0: Obf = bf16(acc)
//   EPI = 2: v = acc + Xres; Xres = v (fp32); Obf = bf16(v)
// ---------------------------------------------------------------------------
template <int K, int NT, int EPI>
__global__ __launch_bounds__(256) void gemm_bf16(
    const unsigned short* __restrict__ A, int lda,
    const unsigned short* __restrict__ Bt, int ldb,
    int ldc,
    unsigned short* __restrict__ Obf,
    float* __restrict__ Xres)
{
    constexpr int BCH   = NT / 8;
    constexpr int NTW   = NT / 32;
    constexpr int STAGE = 8192 + NT * 64;
    constexpr int EPIL  = 128 * (NT + 8);
    constexpr int SMEM  = (STAGE > EPIL) ? STAGE : EPIL;
    __shared__ unsigned short sMem[SMEM];
    unsigned short* sA = sMem;
    unsigned short* sB = sMem + 8192;

    const int tid  = threadIdx.x;
    const int lane = tid & 63;
    const int wave = tid >> 6;
    const int m0 = blockIdx.y * 128;
    const int n0 = blockIdx.x * NT;
    const int wm = (wave >> 1) * 64;
    const int wn = (wave & 1) * (NT / 2);
    const int lm = lane & 15;
    const int lq = lane >> 4;

    const int srow = lane >> 3;
    const int scol = ((lane & 7) ^ srow) * 8;

    f32x4 acc[4][NTW];
    #pragma unroll
    for (int i = 0; i < 4; ++i)
        #pragma unroll
        for (int j = 0; j < NTW; ++j) acc[i][j] = (f32x4){0.f, 0.f, 0.f, 0.f};

    for (int k0 = 0; k0 < K; k0 += 64) {
        #pragma unroll
        for (int c = wave; c < 16; c += 4)
            load_lds16(A + (size_t)(m0 + c * 8 + srow) * lda + k0 + scol, &sA[c * 512]);
        #pragma unroll
        for (int c = wave; c < BCH; c += 4)
            load_lds16(Bt + (size_t)(n0 + c * 8 + srow) * ldb + k0 + scol, &sB[c * 512]);
        __syncthreads();
        #pragma unroll
        for (int ks = 0; ks < 2; ++ks) {
            bf16x8 aF[4], bF[NTW];
            #pragma unroll
            for (int mt = 0; mt < 4; ++mt) {
                const int row = wm + mt * 16 + lm;
                aF[mt] = *(const bf16x8*)&sA[row * 64 + (((ks * 4 + lq) ^ (lm & 7)) * 8)];
            }
            #pragma unroll
            for (int nt = 0; nt < NTW; ++nt) {
                const int row = wn + nt * 16 + lm;
                bF[nt] = *(const bf16x8*)&sB[row * 64 + (((ks * 4 + lq) ^ (lm & 7)) * 8)];
            }
            #pragma unroll
            for (int mt = 0; mt < 4; ++mt)
                #pragma unroll
                for (int nt = 0; nt < NTW; ++nt)
                    acc[mt][nt] = __builtin_amdgcn_mfma_f32_16x16x32_bf16(
                        aF[mt], bF[nt], acc[mt][nt], 0, 0, 0);
        }
        __syncthreads();
    }

    unsigned short* sOut = sMem;
    #pragma unroll
    for (int mt = 0; mt < 4; ++mt) {
        #pragma unroll
        for (int nt = 0; nt < NTW; ++nt) {
            #pragma unroll
            for (int r = 0; r < 4; ++r) {
                const int row = wm + mt * 16 + lq * 4 + r;
                const int col = wn + nt * 16 + lm;
                float v = acc[mt][nt][r];
                if (EPI == 2) {
                    const size_t gi = (size_t)(m0 + row) * ldc + n0 + col;
                    v += Xres[gi];
                    Xres[gi] = v;
                }
                sOut[row * (NT + 8) + col] = f2bf(v);
            }
        }
    }
    __syncthreads();
    #pragma unroll
    for (int j = 0; j < NT / 16; ++j) {
        const int idx = j * 256 + tid;
        const int row = idx / (NT / 8);
        const int cpos = (idx % (NT / 8)) * 8;
        *(bf16x8*)&Obf[(size_t)(m0 + row) * ldc + n0 + cpos] =
            *(const bf16x8*)&sOut[row * (NT + 8) + cpos];
    }
}

// ---------------------------------------------------------------------------
// x_proj: dblsum[M,48] += ub[M,1024] @ Wxt[48,1024]^T, split-K grid, atomics.
// ---------------------------------------------------------------------------
__global__ __launch_bounds__(256) void gemm_xproj(
    const unsigned short* __restrict__ ub,
    const unsigned short* __restrict__ Wxt,
    float* __restrict__ dblsum)
{
    const int tid = threadIdx.x, lane = tid & 63, wave = tid >> 6;
    const int lm = lane & 15, lq = lane >> 4;
    const int rowA = blockIdx.x * 128 + wave * 32;
    const int split = blockIdx.y;
    const int k0 = split * (DINNER / NSPLIT);

    f32x4 acc[2][3];
    #pragma unroll
    for (int i = 0; i < 2; ++i)
        #pragma unroll
        for (int j = 0; j < 3; ++j) acc[i][j] = (f32x4){0.f, 0.f, 0.f, 0.f};

    #pragma unroll
    for (int kk = 0; kk < DINNER / NSPLIT; kk += 32) {
        const int k = k0 + kk;
        bf16x8 aF[2], bF[3];
        #pragma unroll
        for (int mt = 0; mt < 2; ++mt)
            aF[mt] = *(const bf16x8*)&ub[(size_t)(rowA + mt * 16 + lm) * DINNER + k + lq * 8];
        #pragma unroll
        for (int nt = 0; nt < 3; ++nt)
            bF[nt] = *(const bf16x8*)&Wxt[(size_t)(nt * 16 + lm) * DINNER + k + lq * 8];
        #pragma unroll
        for (int mt = 0; mt < 2; ++mt)
            #pragma unroll
            for (int nt = 0; nt < 3; ++nt)
                acc[mt][nt] = __builtin_amdgcn_mfma_f32_16x16x32_bf16(
                    aF[mt], bF[nt], acc[mt][nt], 0, 0, 0);
    }
    #pragma unroll
    for (int mt = 0; mt < 2; ++mt)
        #pragma unroll
        for (int nt = 0; nt < 3; ++nt)
            #pragma unroll
            for (int r = 0; r < 4; ++r)
                atomicAdd(&dblsum[(size_t)(rowA + mt * 16 + lq * 4 + r) * DBLW
                                  + nt * 16 + lm], acc[mt][nt][r]);
}

// ---------------------------------------------------------------------------
// dt_proj fused: delta = bf16(softplus(dblsum[:, :32] @ Wdtt^T + bdt))
// ---------------------------------------------------------------------------
__global__ __launch_bounds__(256) void gemm_dt(
    const float* __restrict__ dblsum,        // (M, 48)
    const unsigned short* __restrict__ Wdtt, // (1024, 32) bf16
    const float* __restrict__ bdt,           // (1024,)
    unsigned short* __restrict__ delta_bf)   // (M, 1024)
{
    const int lane = threadIdx.x & 63;
    const int wave = threadIdx.x >> 6;
    const int lm = lane & 15, lq = lane >> 4;
    const int m0 = blockIdx.y * 64;
    const int colbase = blockIdx.x * 256;
    const int mrow = m0 + wave * 16;

    __shared__ unsigned short sOut[64 * 264];

    const float* p = &dblsum[(size_t)(mrow + lm) * DBLW + lq * 8];
    float4 x0 = *(const float4*)p;
    float4 x1 = *(const float4*)(p + 4);
    bf16x8 aF;
    aF[0] = (short)f2bf(x0.x); aF[1] = (short)f2bf(x0.y);
    aF[2] = (short)f2bf(x0.z); aF[3] = (short)f2bf(x0.w);
    aF[4] = (short)f2bf(x1.x); aF[5] = (short)f2bf(x1.y);
    aF[6] = (short)f2bf(x1.z); aF[7] = (short)f2bf(x1.w);

    #pragma unroll
    for (int nt = 0; nt < 16; ++nt) {
        const int col16 = colbase + nt * 16;
        bf16x8 bF = *(const bf16x8*)&Wdtt[(size_t)(col16 + lm) * DTRANK + lq * 8];
        f32x4 acc = (f32x4){0.f, 0.f, 0.f, 0.f};
        acc = __builtin_amdgcn_mfma_f32_16x16x32_bf16(aF, bF, acc, 0, 0, 0);
        const float bias = bdt[col16 + lm];
        #pragma unroll
        for (int r = 0; r < 4; ++r)
            sOut[(wave * 16 + lq * 4 + r) * 264 + (nt * 16 + lm)] =
                f2bf(softplus_fast(acc[r] + bias));
    }
    __syncthreads();
    #pragma unroll
    for (int j = 0; j < 8; ++j) {
        const int idx = j * 256 + threadIdx.x;
        const int row = idx >> 5;
        const int cpos = (idx & 31) * 8;
        *(bf16x8*)&delta_bf[(size_t)(m0 + row) * DINNER + colbase + cpos] =
            *(const bf16x8*)&sOut[row * 264 + cpos];
    }
}

// ---------------------------------------------------------------------------
// Weight transpose + cast: out[n][k] bf16 = in[k][n] fp32
// ---------------------------------------------------------------------------
__global__ __launch_bounds__(256) void transpose_cast(
    const float* __restrict__ in, unsigned short* __restrict__ out,
    int Kdim, int Ndim, size_t in_stride, size_t out_stride)
{
    __shared__ float s[32][33];
    const float* ip = in + blockIdx.z * in_stride;
    unsigned short* op = out + blockIdx.z * out_stride;
    const int bx = blockIdx.x * 32;
    const int by = blockIdx.y * 32;
    const int t = threadIdx.x;
    const int r = t >> 3;
    const int c4 = (t & 7) * 4;

    const int row = by + r;
    if (bx + c4 + 3 < Ndim) {
        float4 v = *(const float4*)&ip[(size_t)row * Ndim + bx + c4];
        s[r][c4 + 0] = v.x; s[r][c4 + 1] = v.y; s[r][c4 + 2] = v.z; s[r][c4 + 3] = v.w;
    } else {
        for (int i = 0; i < 4; ++i) {
            const int col = bx + c4 + i;
            s[r][c4 + i] = (col < Ndim) ? ip[(size_t)row * Ndim + col] : 0.f;
        }
    }
    __syncthreads();
    if (bx + r < Ndim) {
        unsigned short w0 = f2bf(s[c4 + 0][r]), w1 = f2bf(s[c4 + 1][r]);
        unsigned short w2 = f2bf(s[c4 + 2][r]), w3 = f2bf(s[c4 + 3][r]);
        uint2 pk;
        pk.x = (uint32_t)w0 | ((uint32_t)w1 << 16);
        pk.y = (uint32_t)w2 | ((uint32_t)w3 << 16);
        *(uint2*)&op[(size_t)(bx + r) * Kdim + by + c4] = pk;
    }
}

// fused: x_buf = x_in (fp32 copy) and xb = bf16(x_in)
__global__ void copy_cast(const float* __restrict__ in, float* __restrict__ cpy,
                          unsigned short* __restrict__ outb, int n4) {
    const int i = blockIdx.x * 256 + threadIdx.x;
    if (i >= n4) return;
    float4 v = ((const float4*)in)[i];
    ((float4*)cpy)[i] = v;
    uint2 pk;
    pk.x = (uint32_t)f2bf(v.x) | ((uint32_t)f2bf(v.y) << 16);
    pk.y = (uint32_t)f2bf(v.z) | ((uint32_t)f2bf(v.w) << 16);
    ((uint2*)outb)[i] = pk;
}

// conv weight transpose: cwt[blk][k][d] = cw[blk][d][k]
__global__ void conv_w_transpose(const float* __restrict__ cw, float* __restrict__ cwt) {
    const int i = blockIdx.x * 256 + threadIdx.x;
    if (i >= NBLK * DINNER * KCONV) return;
    const int blk = i >> 12;
    const int rem = i & 4095;
    const int d = rem >> 2;
    const int k = rem & 3;
    cwt[blk * 4096 + k * DINNER + d] = cw[blk * 4096 + d * KCONV + k];
}

// ---------------------------------------------------------------------------
// Depthwise causal conv (K=4) + bias + SiLU; 8 d per thread, bf16x8 I/O.
// Also zeroes dblsum (stream-ordered before gemm_xproj's atomics).
// ---------------------------------------------------------------------------
__global__ __launch_bounds__(256) void conv_silu_kernel(
    const unsigned short* __restrict__ xz,
    const float* __restrict__ cwt,   // (4, 1024)
    const float* __restrict__ cb,
    unsigned short* __restrict__ ub,
    float* __restrict__ dblsum)
{
    const int idx = blockIdx.x * 256 + threadIdx.x;   // over MROWS*128
    if (idx < MROWS * DBLW / 4)
        ((f32x4*)dblsum)[idx] = (f32x4){0.f, 0.f, 0.f, 0.f};

    const int dv = idx & 127;
    const int m  = idx >> 7;
    const int t  = m & (L_SEQ - 1);
    const int d0 = dv * 8;

    float acc[8];
    {
        float4 c0 = *(const float4*)&cb[d0];
        float4 c1 = *(const float4*)&cb[d0 + 4];
        acc[0] = c0.x; acc[1] = c0.y; acc[2] = c0.z; acc[3] = c0.w;
        acc[4] = c1.x; acc[5] = c1.y; acc[6] = c1.z; acc[7] = c1.w;
    }
    #pragma unroll
    for (int k = 0; k < KCONV; ++k) {
        const int tt = t + k - (KCONV - 1);
        if (tt >= 0) {
            bf16x8 xv = *(const bf16x8*)&xz[(size_t)(m - t + tt) * (2 * DINNER) + d0];
            float4 w0 = *(const float4*)&cwt[k * DINNER + d0];
            float4 w1 = *(const float4*)&cwt[k * DINNER + d0 + 4];
            acc[0] = fmaf(bf2f_s(xv[0]), w0.x, acc[0]);
            acc[1] = fmaf(bf2f_s(xv[1]), w0.y, acc[1]);
            acc[2] = fmaf(bf2f_s(xv[2]), w0.z, acc[2]);
            acc[3] = fmaf(bf2f_s(xv[3]), w0.w, acc[3]);
            acc[4] = fmaf(bf2f_s(xv[4]), w1.x, acc[4]);
            acc[5] = fmaf(bf2f_s(xv[5]), w1.y, acc[5]);
            acc[6] = fmaf(bf2f_s(xv[6]), w1.z, acc[6]);
            acc[7] = fmaf(bf2f_s(xv[7]), w1.w, acc[7]);
        }
    }
    bf16x8 o;
    #pragma unroll
    for (int j = 0; j < 8; ++j) o[j] = (short)f2bf(silu_fast(acc[j]));
    *(bf16x8*)&ub[(size_t)m * DINNER + d0] = o;
}

// ---------------------------------------------------------------------------
// 3-phase chunked selective scan; VD=4 channels/thread, LC2=16 rows/chunk.
// ---------------------------------------------------------------------------
__global__ __launch_bounds__(256) void scan_chunk_kernel(
    const unsigned short* __restrict__ delta_bf,
    const unsigned short* __restrict__ ub,
    const float* __restrict__ dblsum,
    const float* __restrict__ A_log,
    float* __restrict__ Pbuf,
    float* __restrict__ Sbuf)
{
    const int c = blockIdx.x;
    const int b = blockIdx.y;
    const int tid = threadIdx.x;
    const int d0 = tid * VD;

    __shared__ float sB[LC2][DSTATE];

    const size_t m0 = (size_t)b * L_SEQ + c * LC2;
    if (tid < LC2 * DSTATE) {
        const int r = tid >> 3, n = tid & 7;
        sB[r][n] = dblsum[(m0 + r) * DBLW + DTRANK + n];
    }
    __syncthreads();

    float a[DSTATE * VD], P[DSTATE * VD], S[DSTATE * VD];
    #pragma unroll
    for (int n = 0; n < DSTATE; ++n)
        #pragma unroll
        for (int v = 0; v < VD; ++v) {
            a[n * VD + v] = -__expf(A_log[(d0 + v) * DSTATE + n]);
            P[n * VD + v] = 1.f;
            S[n * VD + v] = 0.f;
        }

    for (int r = 0; r < LC2; ++r) {
        const size_t m = m0 + r;
        bf16x4 dv = *(const bf16x4*)&delta_bf[m * DINNER + d0];
        bf16x4 uv = *(const bf16x4*)&ub[m * DINNER + d0];
        float dt[VD], du[VD];
        #pragma unroll
        for (int v = 0; v < VD; ++v) {
            dt[v] = bf2f_s(dv[v]);
            du[v] = dt[v] * bf2f_s(uv[v]);
        }
        #pragma unroll
        for (int n = 0; n < DSTATE; ++n) {
            const float bn = sB[r][n];
            #pragma unroll
            for (int v = 0; v < VD; ++v) {
                const float e = __expf(dt[v] * a[n * VD + v]);
                S[n * VD + v] = fmaf(e, S[n * VD + v], du[v] * bn);
                P[n * VD + v] *= e;
            }
        }
    }

    const size_t base = ((size_t)(b * NC2 + c) * DSTATE) * DINNER + d0;
    #pragma unroll
    for (int n = 0; n < DSTATE; ++n) {
        *(float4*)&Pbuf[base + (size_t)n * DINNER] = *(float4*)&P[n * VD];
        *(float4*)&Sbuf[base + (size_t)n * DINNER] = *(float4*)&S[n * VD];
    }
}

// Combine: h-recurrence over chunks, fully parallel over (b, d, n).
// Grid (DINNER/256, DSTATE, BATCH_N) = 128 blocks; coalesced over d.
__global__ __launch_bounds__(256) void scan_combine_kernel(
    float* __restrict__ Pbuf,
    const float* __restrict__ Sbuf)
{
    const int d = blockIdx.x * 256 + threadIdx.x;
    const int n = blockIdx.y;
    const int b = blockIdx.z;

    float h = 0.f;
    #pragma unroll 4
    for (int c = 0; c < NC2; ++c) {
        const size_t idx = ((size_t)(b * NC2 + c) * DSTATE + n) * DINNER + d;
        const float p = Pbuf[idx];
        const float s = Sbuf[idx];
        Pbuf[idx] = h;
        h = fmaf(p, h, s);
    }
}

__global__ __launch_bounds__(256) void scan_out_kernel(
    const unsigned short* __restrict__ delta_bf,
    const unsigned short* __restrict__ ub,
    const float* __restrict__ dblsum,
    const unsigned short* __restrict__ xz,   // z at [., 1024+d]
    const float* __restrict__ A_log,
    const float* __restrict__ Dp,
    const float* __restrict__ Hin,
    unsigned short* __restrict__ ybuf)
{
    const int c = blockIdx.x;
    const int b = blockIdx.y;
    const int tid = threadIdx.x;
    const int d0 = tid * VD;

    __shared__ float sB[LC2][DSTATE];
    __shared__ float sC[LC2][DSTATE];

    const size_t m0 = (size_t)b * L_SEQ + c * LC2;
    if (tid < LC2 * 2 * DSTATE) {
        const int r = tid >> 4, j = tid & 15;
        const float v = dblsum[(m0 + r) * DBLW + DTRANK + j];
        if (j < DSTATE) sB[r][j] = v;
        else            sC[r][j - DSTATE] = v;
    }
    __syncthreads();

    float a[DSTATE * VD], h[DSTATE * VD];
    const size_t base = ((size_t)(b * NC2 + c) * DSTATE) * DINNER + d0;
    #pragma unroll
    for (int n = 0; n < DSTATE; ++n) {
        float4 hv = *(const float4*)&Hin[base + (size_t)n * DINNER];
        h[n * VD + 0] = hv.x; h[n * VD + 1] = hv.y;
        h[n * VD + 2] = hv.z; h[n * VD + 3] = hv.w;
        #pragma unroll
        for (int v = 0; v < VD; ++v)
            a[n * VD + v] = -__expf(A_log[(d0 + v) * DSTATE + n]);
    }
    float Dd[VD];
    {
        float4 dv4 = *(const float4*)&Dp[d0];
        Dd[0] = dv4.x; Dd[1] = dv4.y; Dd[2] = dv4.z; Dd[3] = dv4.w;
    }

    for (int r = 0; r < LC2; ++r) {
        const size_t m = m0 + r;
        bf16x4 dv = *(const bf16x4*)&delta_bf[m * DINNER + d0];
        bf16x4 uv = *(const bf16x4*)&ub[m * DINNER + d0];
        bf16x4 zv = *(const bf16x4*)&xz[m * (2 * DINNER) + DINNER + d0];
        float dt[VD], ut[VD], du[VD], acc[VD];
        #pragma unroll
        for (int v = 0; v < VD; ++v) {
            dt[v] = bf2f_s(dv[v]);
            ut[v] = bf2f_s(uv[v]);
            du[v] = dt[v] * ut[v];
            acc[v] = 0.f;
        }
        #pragma unroll
        for (int n = 0; n < DSTATE; ++n) {
            const float bn = sB[r][n];
            const float cn = sC[r][n];
            #pragma unroll
            for (int v = 0; v < VD; ++v) {
                const float e = __expf(dt[v] * a[n * VD + v]);
                h[n * VD + v] = fmaf(e, h[n * VD + v], du[v] * bn);
                acc[v] = fmaf(h[n * VD + v], cn, acc[v]);
            }
        }
        bf16x4 o;
        #pragma unroll
        for (int v = 0; v < VD; ++v)
            o[v] = (short)f2bf(fmaf(ut[v], Dd[v], acc[v]) * silu_fast(bf2f_s(zv[v])));
        *(bf16x4*)&ybuf[m * DINNER + d0] = o;
    }
}

// ---------------------------------------------------------------------------
#define POOL_SEGS 16
__global__ __launch_bounds__(512) void pool1_kernel(
    const float* __restrict__ x, float* __restrict__ part)
{
    const int b = blockIdx.y;
    const int seg = blockIdx.x;
    const int dm = threadIdx.x;
    const int tpseg = L_SEQ / POOL_SEGS;
    float s = 0.f;
    for (int t = seg * tpseg; t < (seg + 1) * tpseg; ++t)
        s += x[((size_t)b * L_SEQ + t) * DMODEL + dm];
    part[((size_t)b * POOL_SEGS + seg) * DMODEL + dm] = s;
}

// fused pool stage-2 + classifier: grid = BATCH_N, 512 threads
__global__ __launch_bounds__(512) void pool2_cls_kernel(
    const float* __restrict__ part,
    const float* __restrict__ w,     // (512, 10)
    const float* __restrict__ bias,  // (10,)
    float* __restrict__ out)
{
    __shared__ float sp[DMODEL];
    const int b = blockIdx.x;
    const int dm = threadIdx.x;
    float s = 0.f;
    #pragma unroll
    for (int seg = 0; seg < POOL_SEGS; ++seg)
        s += part[((size_t)b * POOL_SEGS + seg) * DMODEL + dm];
    sp[dm] = s * (1.f / (float)L_SEQ);
    __syncthreads();
    if (dm < NCLS_N) {
        float acc = bias[dm];
        for (int k = 0; k < DMODEL; ++k)
            acc = fmaf(sp[k], w[k * NCLS_N + dm], acc);
        out[b * NCLS_N + dm] = acc;
    }
}

// ---------------------------------------------------------------------------
extern "C" void kernel_launch(void* const* d_in, const int* in_sizes, int n_in,
                              void* d_out, int out_size, void* d_ws, size_t ws_size,
                              hipStream_t stream) {
    const float* x_in      = (const float*)d_in[0];
    const float* in_proj_w = (const float*)d_in[1];
    const float* conv_w    = (const float*)d_in[2];
    const float* conv_b    = (const float*)d_in[3];
    const float* x_proj_w  = (const float*)d_in[4];
    const float* dt_proj_w = (const float*)d_in[5];
    const float* dt_proj_b = (const float*)d_in[6];
    const float* A_log     = (const float*)d_in[7];
    const float* Dp        = (const float*)d_in[8];
    const float* out_proj_w= (const float*)d_in[9];
    const float* cls_w     = (const float*)d_in[10];
    const float* cls_b     = (const float*)d_in[11];
    float* out = (float*)d_out;

    // Workspace layout (bytes, 256-aligned)
    char* w = (char*)d_ws;
    auto alloc = [&](size_t bytes) { char* p = w; w += (bytes + 255) & ~(size_t)255; return p; };
    float*          x_buf  = (float*)         alloc((size_t)MROWS * DMODEL * 4);
    unsigned short* xz_bf  = (unsigned short*)alloc((size_t)MROWS * 2 * DINNER * 2);
    unsigned short* ub     = (unsigned short*)alloc((size_t)MROWS * DINNER * 2);
    unsigned short* delta  = (unsigned short*)alloc((size_t)MROWS * DINNER * 2);
    float*          dblsum = (float*)         alloc((size_t)MROWS * DBLW * 4);
    float*          Pbuf   = (float*)         alloc((size_t)BATCH_N * NC2 * DSTATE * DINNER * 4);
    float*          Sbuf   = (float*)         alloc((size_t)BATCH_N * NC2 * DSTATE * DINNER * 4);
    unsigned short* xb     = (unsigned short*)alloc((size_t)MROWS * DMODEL * 2);
    unsigned short* ybuf   = (unsigned short*)alloc((size_t)MROWS * DINNER * 2);
    unsigned short* Wit    = (unsigned short*)alloc((size_t)NBLK * 2048 * 512 * 2);
    unsigned short* Wot    = (unsigned short*)alloc((size_t)NBLK * 512 * 1024 * 2);
    unsigned short* Wxt    = (unsigned short*)alloc((size_t)NBLK * DBLW * 1024 * 2);
    unsigned short* Wdtt   = (unsigned short*)alloc((size_t)NBLK * 1024 * DTRANK * 2);
    float*          cwt    = (float*)         alloc((size_t)NBLK * KCONV * DINNER * 4);
    float*          part   = (float*)         alloc((size_t)BATCH_N * POOL_SEGS * DMODEL * 4);

    // Prep
    copy_cast<<<(MROWS * DMODEL / 4) / 256, 256, 0, stream>>>(
        x_in, x_buf, xb, MROWS * DMODEL / 4);
    transpose_cast<<<dim3(2048 / 32, 512 / 32, NBLK), 256, 0, stream>>>(
        in_proj_w, Wit, 512, 2048, (size_t)512 * 2048, (size_t)2048 * 512);
    transpose_cast<<<dim3(512 / 32, 1024 / 32, NBLK), 256, 0, stream>>>(
        out_proj_w, Wot, 1024, 512, (size_t)1024 * 512, (size_t)512 * 1024);
    transpose_cast<<<dim3(2, 1024 / 32, NBLK), 256, 0, stream>>>(
        x_proj_w, Wxt, 1024, DBLW, (size_t)1024 * DBLW, (size_t)DBLW * 1024);
    transpose_cast<<<dim3(1024 / 32, 1, NBLK), 256, 0, stream>>>(
        dt_proj_w, Wdtt, DTRANK, 1024, (size_t)DTRANK * 1024, (size_t)1024 * DTRANK);
    conv_w_transpose<<<(NBLK * DINNER * KCONV + 255) / 256, 256, 0, stream>>>(conv_w, cwt);

    for (int blk = 0; blk < NBLK; ++blk) {
        const unsigned short* Wit_b  = Wit  + (size_t)blk * 2048 * 512;
        const unsigned short* Wot_b  = Wot  + (size_t)blk * 512 * 1024;
        const unsigned short* Wxt_b  = Wxt  + (size_t)blk * DBLW * 1024;
        const unsigned short* Wdtt_b = Wdtt + (size_t)blk * 1024 * DTRANK;
        const float* cwt_b = cwt + (size_t)blk * KCONV * DINNER;
        const float* cb  = conv_b    + (size_t)blk * DINNER;
        const float* bdt = dt_proj_b + (size_t)blk * DINNER;
        const float* Al  = A_log     + (size_t)blk * DINNER * DSTATE;
        const float* Dv  = Dp        + (size_t)blk * DINNER;

        // 1) xz_bf = bf16(xb @ Wit^T)   K=512, 128x128 tiles
        gemm_bf16<512, 128, 0><<<dim3(2048 / 128, MROWS / 128), 256, 0, stream>>>(
            xb, DMODEL, Wit_b, DMODEL, 2 * DINNER, xz_bf, nullptr);
        // 2) ub = bf16(silu(conv(xz_bf lo) + cb)); zeroes dblsum
        conv_silu_kernel<<<(MROWS * 128) / 256, 256, 0, stream>>>(
            xz_bf, cwt_b, cb, ub, dblsum);
        // 3) dblsum += ub @ Wxt^T (split-K grid x8, atomics)
        gemm_xproj<<<dim3(MROWS / 128, NSPLIT), 256, 0, stream>>>(ub, Wxt_b, dblsum);
        // 4) delta = bf16(softplus(dblsum[:, :32] @ Wdtt^T + bdt))
        gemm_dt<<<dim3(DINNER / 256, MROWS / 64), 256, 0, stream>>>(
            dblsum, Wdtt_b, bdt, delta);
        // 5) chunked scan (LC2=16 -> 512 blocks; combine parallel over (b,d,n))
        {
            dim3 gridA(NC2, BATCH_N);
            scan_chunk_kernel<<<gridA, 256, 0, stream>>>(delta, ub, dblsum, Al, Pbuf, Sbuf);
            scan_combine_kernel<<<dim3(DINNER / 256, DSTATE, BATCH_N), 256, 0, stream>>>(
                Pbuf, Sbuf);
            scan_out_kernel<<<gridA, 256, 0, stream>>>(delta, ub, dblsum, xz_bf, Al, Dv, Pbuf, ybuf);
        }
        // 6) x_buf += ybuf @ Wot^T; xb = bf16(x_buf)   K=1024, 128x64 tiles
        gemm_bf16<1024, 64, 2><<<dim3(DMODEL / 64, MROWS / 128), 256, 0, stream>>>(
            ybuf, DINNER, Wot_b, DINNER, DMODEL, xb, x_buf);
    }

    // mean pool + classifier
    {
        dim3 grid1(POOL_SEGS, BATCH_N);
        pool1_kernel<<<grid1, DMODEL, 0, stream>>>(x_buf, part);
        pool2_cls_kernel<<<BATCH_N, DMODEL, 0, stream>>>(part, cls_w, cls_b, out);
    }
}

// Round 12
// 571.632 us; speedup vs baseline: 1.3509x; 1.1453x over previous
//
#include <hip/hip_runtime.h>
#include <cstddef>
#include <cstdint>

// Problem constants
#define L_SEQ   2048
#define BATCH_N 4
#define DMODEL  512
#define DINNER  1024
#define DSTATE  8
#define KCONV   4
#define DTRANK  32
#define NBLK    3
#define NCLS_N  10
#define MROWS   (BATCH_N * L_SEQ)   // 8192
#define DBLW    48                  // dt_rank + 2*d_state
#define NSPLIT  8                   // x_proj split-K grid (8 -> 512 blocks, 2/CU)

// Chunked-scan parameters: LC2=16 rows/chunk -> 512 blocks (2/CU, 8 waves/CU)
#define LC2 16
#define NC2 (L_SEQ / LC2)   // 128
#define VD  4

typedef __attribute__((ext_vector_type(8))) short bf16x8;
typedef __attribute__((ext_vector_type(4))) short bf16x4;
typedef __attribute__((ext_vector_type(4))) float f32x4;

// Fast inline transcendentals (v_exp_f32 / v_log_f32 — no ocml calls).
__device__ __forceinline__ float sigmoid_fast(float x) { return 1.f / (1.f + __expf(-x)); }
__device__ __forceinline__ float silu_fast(float x)    { return x * sigmoid_fast(x); }
__device__ __forceinline__ float softplus_fast(float x){
    return fmaxf(x, 0.f) + __logf(1.f + __expf(-fabsf(x)));
}

__device__ __forceinline__ unsigned short f2bf(float f) {
    union { float f; uint32_t u; } v; v.f = f;
    const uint32_t u = v.u;
    return (unsigned short)((u + 0x7fffu + ((u >> 16) & 1u)) >> 16);  // RNE
}
__device__ __forceinline__ float bf2f(unsigned short h) {
    union { uint32_t u; float f; } v; v.u = ((uint32_t)h) << 16;
    return v.f;
}
__device__ __forceinline__ float bf2f_s(short h) { return bf2f((unsigned short)h); }

// async global -> LDS, 16 bytes per lane
__device__ __forceinline__ void load_lds16(const void* g, void* l) {
    __builtin_amdgcn_global_load_lds(
        (const __attribute__((address_space(1))) unsigned int*)g,
        (__attribute__((address_space(3))) unsigned int*)l,
        16, 0, 0);
}

// ---------------------------------------------------------------------------
// bf16 MFMA GEMM: acc = A[M,K] @ Bt[N,K]^T, 128 x NT tile, BK=64, 256 thr.
// Single-buffered staging; XOR-swizzled LDS; LDS-bounced coalesced epilogue.
//   EPI = 0: Obf = bf16(acc)
//   EPI = 2: v = acc + bf2f(Obf) (bf16 residual, in-place)
//   EPI = 3: as 2, plus column sums atomicAdd'ed into pool[b][col] (mean-pool
//            fusion for the final out_proj; NT must be 64)
// ---------------------------------------------------------------------------
template <int K, int NT, int EPI>
__global__ __launch_bounds__(256) void gemm_bf16(
    const unsigned short* __restrict__ A, int lda,
    const unsigned short* __restrict__ Bt, int ldb,
    int ldc,
    unsigned short* __restrict__ Obf,
    float* __restrict__ pool)
{
    constexpr int BCH   = NT / 8;
    constexpr int NTW   = NT / 32;
    constexpr int STAGE = 8192 + NT * 64;
    constexpr int EPIL  = 128 * (NT + 8);
    constexpr int SMEM  = (STAGE > EPIL) ? STAGE : EPIL;
    __shared__ unsigned short sMem[SMEM];
    unsigned short* sA = sMem;
    unsigned short* sB = sMem + 8192;

    const int tid  = threadIdx.x;
    const int lane = tid & 63;
    const int wave = tid >> 6;
    const int m0 = blockIdx.y * 128;
    const int n0 = blockIdx.x * NT;
    const int wm = (wave >> 1) * 64;
    const int wn = (wave & 1) * (NT / 2);
    const int lm = lane & 15;
    const int lq = lane >> 4;

    const int srow = lane >> 3;
    const int scol = ((lane & 7) ^ srow) * 8;

    f32x4 acc[4][NTW];
    #pragma unroll
    for (int i = 0; i < 4; ++i)
        #pragma unroll
        for (int j = 0; j < NTW; ++j) acc[i][j] = (f32x4){0.f, 0.f, 0.f, 0.f};

    for (int k0 = 0; k0 < K; k0 += 64) {
        #pragma unroll
        for (int c = wave; c < 16; c += 4)
            load_lds16(A + (size_t)(m0 + c * 8 + srow) * lda + k0 + scol, &sA[c * 512]);
        #pragma unroll
        for (int c = wave; c < BCH; c += 4)
            load_lds16(Bt + (size_t)(n0 + c * 8 + srow) * ldb + k0 + scol, &sB[c * 512]);
        __syncthreads();
        #pragma unroll
        for (int ks = 0; ks < 2; ++ks) {
            bf16x8 aF[4], bF[NTW];
            #pragma unroll
            for (int mt = 0; mt < 4; ++mt) {
                const int row = wm + mt * 16 + lm;
                aF[mt] = *(const bf16x8*)&sA[row * 64 + (((ks * 4 + lq) ^ (lm & 7)) * 8)];
            }
            #pragma unroll
            for (int nt = 0; nt < NTW; ++nt) {
                const int row = wn + nt * 16 + lm;
                bF[nt] = *(const bf16x8*)&sB[row * 64 + (((ks * 4 + lq) ^ (lm & 7)) * 8)];
            }
            #pragma unroll
            for (int mt = 0; mt < 4; ++mt)
                #pragma unroll
                for (int nt = 0; nt < NTW; ++nt)
                    acc[mt][nt] = __builtin_amdgcn_mfma_f32_16x16x32_bf16(
                        aF[mt], bF[nt], acc[mt][nt], 0, 0, 0);
        }
        __syncthreads();
    }

    unsigned short* sOut = sMem;
    #pragma unroll
    for (int mt = 0; mt < 4; ++mt) {
        #pragma unroll
        for (int nt = 0; nt < NTW; ++nt) {
            #pragma unroll
            for (int r = 0; r < 4; ++r) {
                const int row = wm + mt * 16 + lq * 4 + r;
                const int col = wn + nt * 16 + lm;
                float v = acc[mt][nt][r];
                if (EPI >= 2) {
                    const size_t gi = (size_t)(m0 + row) * ldc + n0 + col;
                    v += bf2f(Obf[gi]);   // bf16 residual read (write comes after barrier)
                }
                sOut[row * (NT + 8) + col] = f2bf(v);
            }
        }
    }
    __syncthreads();
    #pragma unroll
    for (int j = 0; j < NT / 16; ++j) {
        const int idx = j * 256 + tid;
        const int row = idx / (NT / 8);
        const int cpos = (idx % (NT / 8)) * 8;
        *(bf16x8*)&Obf[(size_t)(m0 + row) * ldc + n0 + cpos] =
            *(const bf16x8*)&sOut[row * (NT + 8) + cpos];
    }
    if (EPI == 3) {
        // mean-pool fusion: sum the 128-row tile per column (4 partials/col)
        const int b = m0 >> 11;        // m0 / 2048 (tiles never cross batch)
        const int col = tid & (NT - 1);
        const int q = tid / NT;        // 0..(256/NT - 1)
        constexpr int RPQ = 128 / (256 / NT);
        float s = 0.f;
        #pragma unroll
        for (int r = q * RPQ; r < (q + 1) * RPQ; ++r)
            s += bf2f(sOut[r * (NT + 8) + col]);
        atomicAdd(&pool[b * DMODEL + n0 + col], s);
    }
}

// ---------------------------------------------------------------------------
// x_proj: dblsum[M,48] += ub[M,1024] @ Wxt[48,1024]^T, split-K grid, atomics.
// ---------------------------------------------------------------------------
__global__ __launch_bounds__(256) void gemm_xproj(
    const unsigned short* __restrict__ ub,
    const unsigned short* __restrict__ Wxt,
    float* __restrict__ dblsum)
{
    const int tid = threadIdx.x, lane = tid & 63, wave = tid >> 6;
    const int lm = lane & 15, lq = lane >> 4;
    const int rowA = blockIdx.x * 128 + wave * 32;
    const int split = blockIdx.y;
    const int k0 = split * (DINNER / NSPLIT);

    f32x4 acc[2][3];
    #pragma unroll
    for (int i = 0; i < 2; ++i)
        #pragma unroll
        for (int j = 0; j < 3; ++j) acc[i][j] = (f32x4){0.f, 0.f, 0.f, 0.f};

    #pragma unroll
    for (int kk = 0; kk < DINNER / NSPLIT; kk += 32) {
        const int k = k0 + kk;
        bf16x8 aF[2], bF[3];
        #pragma unroll
        for (int mt = 0; mt < 2; ++mt)
            aF[mt] = *(const bf16x8*)&ub[(size_t)(rowA + mt * 16 + lm) * DINNER + k + lq * 8];
        #pragma unroll
        for (int nt = 0; nt < 3; ++nt)
            bF[nt] = *(const bf16x8*)&Wxt[(size_t)(nt * 16 + lm) * DINNER + k + lq * 8];
        #pragma unroll
        for (int mt = 0; mt < 2; ++mt)
            #pragma unroll
            for (int nt = 0; nt < 3; ++nt)
                acc[mt][nt] = __builtin_amdgcn_mfma_f32_16x16x32_bf16(
                    aF[mt], bF[nt], acc[mt][nt], 0, 0, 0);
    }
    #pragma unroll
    for (int mt = 0; mt < 2; ++mt)
        #pragma unroll
        for (int nt = 0; nt < 3; ++nt)
            #pragma unroll
            for (int r = 0; r < 4; ++r)
                atomicAdd(&dblsum[(size_t)(rowA + mt * 16 + lq * 4 + r) * DBLW
                                  + nt * 16 + lm], acc[mt][nt][r]);
}

// ---------------------------------------------------------------------------
// dt_proj fused: delta = bf16(softplus(dblsum[:, :32] @ Wdtt^T + bdt))
// ---------------------------------------------------------------------------
__global__ __launch_bounds__(256) void gemm_dt(
    const float* __restrict__ dblsum,        // (M, 48)
    const unsigned short* __restrict__ Wdtt, // (1024, 32) bf16
    const float* __restrict__ bdt,           // (1024,)
    unsigned short* __restrict__ delta_bf)   // (M, 1024)
{
    const int lane = threadIdx.x & 63;
    const int wave = threadIdx.x >> 6;
    const int lm = lane & 15, lq = lane >> 4;
    const int m0 = blockIdx.y * 64;
    const int colbase = blockIdx.x * 256;
    const int mrow = m0 + wave * 16;

    __shared__ unsigned short sOut[64 * 264];

    const float* p = &dblsum[(size_t)(mrow + lm) * DBLW + lq * 8];
    float4 x0 = *(const float4*)p;
    float4 x1 = *(const float4*)(p + 4);
    bf16x8 aF;
    aF[0] = (short)f2bf(x0.x); aF[1] = (short)f2bf(x0.y);
    aF[2] = (short)f2bf(x0.z); aF[3] = (short)f2bf(x0.w);
    aF[4] = (short)f2bf(x1.x); aF[5] = (short)f2bf(x1.y);
    aF[6] = (short)f2bf(x1.z); aF[7] = (short)f2bf(x1.w);

    #pragma unroll
    for (int nt = 0; nt < 16; ++nt) {
        const int col16 = colbase + nt * 16;
        bf16x8 bF = *(const bf16x8*)&Wdtt[(size_t)(col16 + lm) * DTRANK + lq * 8];
        f32x4 acc = (f32x4){0.f, 0.f, 0.f, 0.f};
        acc = __builtin_amdgcn_mfma_f32_16x16x32_bf16(aF, bF, acc, 0, 0, 0);
        const float bias = bdt[col16 + lm];
        #pragma unroll
        for (int r = 0; r < 4; ++r)
            sOut[(wave * 16 + lq * 4 + r) * 264 + (nt * 16 + lm)] =
                f2bf(softplus_fast(acc[r] + bias));
    }
    __syncthreads();
    #pragma unroll
    for (int j = 0; j < 8; ++j) {
        const int idx = j * 256 + threadIdx.x;
        const int row = idx >> 5;
        const int cpos = (idx & 31) * 8;
        *(bf16x8*)&delta_bf[(size_t)(m0 + row) * DINNER + colbase + cpos] =
            *(const bf16x8*)&sOut[row * 264 + cpos];
    }
}

// ---------------------------------------------------------------------------
// Weight transpose + cast: out[n][k] bf16 = in[k][n] fp32
// ---------------------------------------------------------------------------
__global__ __launch_bounds__(256) void transpose_cast(
    const float* __restrict__ in, unsigned short* __restrict__ out,
    int Kdim, int Ndim, size_t in_stride, size_t out_stride)
{
    __shared__ float s[32][33];
    const float* ip = in + blockIdx.z * in_stride;
    unsigned short* op = out + blockIdx.z * out_stride;
    const int bx = blockIdx.x * 32;
    const int by = blockIdx.y * 32;
    const int t = threadIdx.x;
    const int r = t >> 3;
    const int c4 = (t & 7) * 4;

    const int row = by + r;
    if (bx + c4 + 3 < Ndim) {
        float4 v = *(const float4*)&ip[(size_t)row * Ndim + bx + c4];
        s[r][c4 + 0] = v.x; s[r][c4 + 1] = v.y; s[r][c4 + 2] = v.z; s[r][c4 + 3] = v.w;
    } else {
        for (int i = 0; i < 4; ++i) {
            const int col = bx + c4 + i;
            s[r][c4 + i] = (col < Ndim) ? ip[(size_t)row * Ndim + col] : 0.f;
        }
    }
    __syncthreads();
    if (bx + r < Ndim) {
        unsigned short w0 = f2bf(s[c4 + 0][r]), w1 = f2bf(s[c4 + 1][r]);
        unsigned short w2 = f2bf(s[c4 + 2][r]), w3 = f2bf(s[c4 + 3][r]);
        uint2 pk;
        pk.x = (uint32_t)w0 | ((uint32_t)w1 << 16);
        pk.y = (uint32_t)w2 | ((uint32_t)w3 << 16);
        *(uint2*)&op[(size_t)(bx + r) * Kdim + by + c4] = pk;
    }
}

// cast x -> xb (bf16) and zero pooled_accum
__global__ void cast_init(const float* __restrict__ in, unsigned short* __restrict__ outb,
                          float* __restrict__ pooled_accum, int n4) {
    const int i = blockIdx.x * 256 + threadIdx.x;
    if (i < BATCH_N * DMODEL / 4)
        ((f32x4*)pooled_accum)[i] = (f32x4){0.f, 0.f, 0.f, 0.f};
    if (i >= n4) return;
    float4 v = ((const float4*)in)[i];
    uint2 pk;
    pk.x = (uint32_t)f2bf(v.x) | ((uint32_t)f2bf(v.y) << 16);
    pk.y = (uint32_t)f2bf(v.z) | ((uint32_t)f2bf(v.w) << 16);
    ((uint2*)outb)[i] = pk;
}

// conv weight transpose: cwt[blk][k][d] = cw[blk][d][k]
__global__ void conv_w_transpose(const float* __restrict__ cw, float* __restrict__ cwt) {
    const int i = blockIdx.x * 256 + threadIdx.x;
    if (i >= NBLK * DINNER * KCONV) return;
    const int blk = i >> 12;
    const int rem = i & 4095;
    const int d = rem >> 2;
    const int k = rem & 3;
    cwt[blk * 4096 + k * DINNER + d] = cw[blk * 4096 + d * KCONV + k];
}

// ---------------------------------------------------------------------------
// Depthwise causal conv (K=4) + bias + SiLU; 8 d per thread, bf16x8 I/O.
// Also zeroes dblsum (stream-ordered before gemm_xproj's atomics).
// ---------------------------------------------------------------------------
__global__ __launch_bounds__(256) void conv_silu_kernel(
    const unsigned short* __restrict__ xz,
    const float* __restrict__ cwt,   // (4, 1024)
    const float* __restrict__ cb,
    unsigned short* __restrict__ ub,
    float* __restrict__ dblsum)
{
    const int idx = blockIdx.x * 256 + threadIdx.x;   // over MROWS*128
    if (idx < MROWS * DBLW / 4)
        ((f32x4*)dblsum)[idx] = (f32x4){0.f, 0.f, 0.f, 0.f};

    const int dv = idx & 127;
    const int m  = idx >> 7;
    const int t  = m & (L_SEQ - 1);
    const int d0 = dv * 8;

    float acc[8];
    {
        float4 c0 = *(const float4*)&cb[d0];
        float4 c1 = *(const float4*)&cb[d0 + 4];
        acc[0] = c0.x; acc[1] = c0.y; acc[2] = c0.z; acc[3] = c0.w;
        acc[4] = c1.x; acc[5] = c1.y; acc[6] = c1.z; acc[7] = c1.w;
    }
    #pragma unroll
    for (int k = 0; k < KCONV; ++k) {
        const int tt = t + k - (KCONV - 1);
        if (tt >= 0) {
            bf16x8 xv = *(const bf16x8*)&xz[(size_t)(m - t + tt) * (2 * DINNER) + d0];
            float4 w0 = *(const float4*)&cwt[k * DINNER + d0];
            float4 w1 = *(const float4*)&cwt[k * DINNER + d0 + 4];
            acc[0] = fmaf(bf2f_s(xv[0]), w0.x, acc[0]);
            acc[1] = fmaf(bf2f_s(xv[1]), w0.y, acc[1]);
            acc[2] = fmaf(bf2f_s(xv[2]), w0.z, acc[2]);
            acc[3] = fmaf(bf2f_s(xv[3]), w0.w, acc[3]);
            acc[4] = fmaf(bf2f_s(xv[4]), w1.x, acc[4]);
            acc[5] = fmaf(bf2f_s(xv[5]), w1.y, acc[5]);
            acc[6] = fmaf(bf2f_s(xv[6]), w1.z, acc[6]);
            acc[7] = fmaf(bf2f_s(xv[7]), w1.w, acc[7]);
        }
    }
    bf16x8 o;
    #pragma unroll
    for (int j = 0; j < 8; ++j) o[j] = (short)f2bf(silu_fast(acc[j]));
    *(bf16x8*)&ub[(size_t)m * DINNER + d0] = o;
}

// ---------------------------------------------------------------------------
// 3-phase chunked selective scan; VD=4 channels/thread, LC2=16 rows/chunk.
// ---------------------------------------------------------------------------
__global__ __launch_bounds__(256) void scan_chunk_kernel(
    const unsigned short* __restrict__ delta_bf,
    const unsigned short* __restrict__ ub,
    const float* __restrict__ dblsum,
    const float* __restrict__ A_log,
    float* __restrict__ Pbuf,
    float* __restrict__ Sbuf)
{
    const int c = blockIdx.x;
    const int b = blockIdx.y;
    const int tid = threadIdx.x;
    const int d0 = tid * VD;

    __shared__ float sB[LC2][DSTATE];

    const size_t m0 = (size_t)b * L_SEQ + c * LC2;
    if (tid < LC2 * DSTATE) {
        const int r = tid >> 3, n = tid & 7;
        sB[r][n] = dblsum[(m0 + r) * DBLW + DTRANK + n];
    }
    __syncthreads();

    float a[DSTATE * VD], P[DSTATE * VD], S[DSTATE * VD];
    #pragma unroll
    for (int n = 0; n < DSTATE; ++n)
        #pragma unroll
        for (int v = 0; v < VD; ++v) {
            a[n * VD + v] = -__expf(A_log[(d0 + v) * DSTATE + n]);
            P[n * VD + v] = 1.f;
            S[n * VD + v] = 0.f;
        }

    for (int r = 0; r < LC2; ++r) {
        const size_t m = m0 + r;
        bf16x4 dv = *(const bf16x4*)&delta_bf[m * DINNER + d0];
        bf16x4 uv = *(const bf16x4*)&ub[m * DINNER + d0];
        float dt[VD], du[VD];
        #pragma unroll
        for (int v = 0; v < VD; ++v) {
            dt[v] = bf2f_s(dv[v]);
            du[v] = dt[v] * bf2f_s(uv[v]);
        }
        #pragma unroll
        for (int n = 0; n < DSTATE; ++n) {
            const float bn = sB[r][n];
            #pragma unroll
            for (int v = 0; v < VD; ++v) {
                const float e = __expf(dt[v] * a[n * VD + v]);
                S[n * VD + v] = fmaf(e, S[n * VD + v], du[v] * bn);
                P[n * VD + v] *= e;
            }
        }
    }

    const size_t base = ((size_t)(b * NC2 + c) * DSTATE) * DINNER + d0;
    #pragma unroll
    for (int n = 0; n < DSTATE; ++n) {
        *(float4*)&Pbuf[base + (size_t)n * DINNER] = *(float4*)&P[n * VD];
        *(float4*)&Sbuf[base + (size_t)n * DINNER] = *(float4*)&S[n * VD];
    }
}

// Combine: h-recurrence over chunks, fully parallel over (b, d, n).
__global__ __launch_bounds__(256) void scan_combine_kernel(
    float* __restrict__ Pbuf,
    const float* __restrict__ Sbuf)
{
    const int d = blockIdx.x * 256 + threadIdx.x;
    const int n = blockIdx.y;
    const int b = blockIdx.z;

    float h = 0.f;
    #pragma unroll 4
    for (int c = 0; c < NC2; ++c) {
        const size_t idx = ((size_t)(b * NC2 + c) * DSTATE + n) * DINNER + d;
        const float p = Pbuf[idx];
        const float s = Sbuf[idx];
        Pbuf[idx] = h;
        h = fmaf(p, h, s);
    }
}

__global__ __launch_bounds__(256) void scan_out_kernel(
    const unsigned short* __restrict__ delta_bf,
    const unsigned short* __restrict__ ub,
    const float* __restrict__ dblsum,
    const unsigned short* __restrict__ xz,   // z at [., 1024+d]
    const float* __restrict__ A_log,
    const float* __restrict__ Dp,
    const float* __restrict__ Hin,
    unsigned short* __restrict__ ybuf)
{
    const int c = blockIdx.x;
    const int b = blockIdx.y;
    const int tid = threadIdx.x;
    const int d0 = tid * VD;

    __shared__ float sB[LC2][DSTATE];
    __shared__ float sC[LC2][DSTATE];

    const size_t m0 = (size_t)b * L_SEQ + c * LC2;
    if (tid < LC2 * 2 * DSTATE) {
        const int r = tid >> 4, j = tid & 15;
        const float v = dblsum[(m0 + r) * DBLW + DTRANK + j];
        if (j < DSTATE) sB[r][j] = v;
        else            sC[r][j - DSTATE] = v;
    }
    __syncthreads();

    float a[DSTATE * VD], h[DSTATE * VD];
    const size_t base = ((size_t)(b * NC2 + c) * DSTATE) * DINNER + d0;
    #pragma unroll
    for (int n = 0; n < DSTATE; ++n) {
        float4 hv = *(const float4*)&Hin[base + (size_t)n * DINNER];
        h[n * VD + 0] = hv.x; h[n * VD + 1] = hv.y;
        h[n * VD + 2] = hv.z; h[n * VD + 3] = hv.w;
        #pragma unroll
        for (int v = 0; v < VD; ++v)
            a[n * VD + v] = -__expf(A_log[(d0 + v) * DSTATE + n]);
    }
    float Dd[VD];
    {
        float4 dv4 = *(const float4*)&Dp[d0];
        Dd[0] = dv4.x; Dd[1] = dv4.y; Dd[2] = dv4.z; Dd[3] = dv4.w;
    }

    for (int r = 0; r < LC2; ++r) {
        const size_t m = m0 + r;
        bf16x4 dv = *(const bf16x4*)&delta_bf[m * DINNER + d0];
        bf16x4 uv = *(const bf16x4*)&ub[m * DINNER + d0];
        bf16x4 zv = *(const bf16x4*)&xz[m * (2 * DINNER) + DINNER + d0];
        float dt[VD], ut[VD], du[VD], acc[VD];
        #pragma unroll
        for (int v = 0; v < VD; ++v) {
            dt[v] = bf2f_s(dv[v]);
            ut[v] = bf2f_s(uv[v]);
            du[v] = dt[v] * ut[v];
            acc[v] = 0.f;
        }
        #pragma unroll
        for (int n = 0; n < DSTATE; ++n) {
            const float bn = sB[r][n];
            const float cn = sC[r][n];
            #pragma unroll
            for (int v = 0; v < VD; ++v) {
                const float e = __expf(dt[v] * a[n * VD + v]);
                h[n * VD + v] = fmaf(e, h[n * VD + v], du[v] * bn);
                acc[v] = fmaf(h[n * VD + v], cn, acc[v]);
            }
        }
        bf16x4 o;
        #pragma unroll
        for (int v = 0; v < VD; ++v)
            o[v] = (short)f2bf(fmaf(ut[v], Dd[v], acc[v]) * silu_fast(bf2f_s(zv[v])));
        *(bf16x4*)&ybuf[m * DINNER + d0] = o;
    }
}

// ---------------------------------------------------------------------------
// pooled-sum (from fused out_proj accumulation) + classifier
// ---------------------------------------------------------------------------
__global__ __launch_bounds__(512) void pool_cls_kernel(
    const float* __restrict__ pooled_accum,   // (B, 512) sums over t
    const float* __restrict__ w,              // (512, 10)
    const float* __restrict__ bias,           // (10,)
    float* __restrict__ out)
{
    __shared__ float sp[DMODEL];
    const int b = blockIdx.x;
    const int dm = threadIdx.x;
    sp[dm] = pooled_accum[b * DMODEL + dm] * (1.f / (float)L_SEQ);
    __syncthreads();
    if (dm < NCLS_N) {
        float acc = bias[dm];
        for (int k = 0; k < DMODEL; ++k)
            acc = fmaf(sp[k], w[k * NCLS_N + dm], acc);
        out[b * NCLS_N + dm] = acc;
    }
}

// ---------------------------------------------------------------------------
extern "C" void kernel_launch(void* const* d_in, const int* in_sizes, int n_in,
                              void* d_out, int out_size, void* d_ws, size_t ws_size,
                              hipStream_t stream) {
    const float* x_in      = (const float*)d_in[0];
    const float* in_proj_w = (const float*)d_in[1];
    const float* conv_w    = (const float*)d_in[2];
    const float* conv_b    = (const float*)d_in[3];
    const float* x_proj_w  = (const float*)d_in[4];
    const float* dt_proj_w = (const float*)d_in[5];
    const float* dt_proj_b = (const float*)d_in[6];
    const float* A_log     = (const float*)d_in[7];
    const float* Dp        = (const float*)d_in[8];
    const float* out_proj_w= (const float*)d_in[9];
    const float* cls_w     = (const float*)d_in[10];
    const float* cls_b     = (const float*)d_in[11];
    float* out = (float*)d_out;

    // Workspace layout (bytes, 256-aligned)
    char* w = (char*)d_ws;
    auto alloc = [&](size_t bytes) { char* p = w; w += (bytes + 255) & ~(size_t)255; return p; };
    unsigned short* xz_bf  = (unsigned short*)alloc((size_t)MROWS * 2 * DINNER * 2);
    unsigned short* ub     = (unsigned short*)alloc((size_t)MROWS * DINNER * 2);
    unsigned short* delta  = (unsigned short*)alloc((size_t)MROWS * DINNER * 2);
    float*          dblsum = (float*)         alloc((size_t)MROWS * DBLW * 4);
    float*          Pbuf   = (float*)         alloc((size_t)BATCH_N * NC2 * DSTATE * DINNER * 4);
    float*          Sbuf   = (float*)         alloc((size_t)BATCH_N * NC2 * DSTATE * DINNER * 4);
    unsigned short* xb     = (unsigned short*)alloc((size_t)MROWS * DMODEL * 2);
    unsigned short* ybuf   = (unsigned short*)alloc((size_t)MROWS * DINNER * 2);
    unsigned short* Wit    = (unsigned short*)alloc((size_t)NBLK * 2048 * 512 * 2);
    unsigned short* Wot    = (unsigned short*)alloc((size_t)NBLK * 512 * 1024 * 2);
    unsigned short* Wxt    = (unsigned short*)alloc((size_t)NBLK * DBLW * 1024 * 2);
    unsigned short* Wdtt   = (unsigned short*)alloc((size_t)NBLK * 1024 * DTRANK * 2);
    float*          cwt    = (float*)         alloc((size_t)NBLK * KCONV * DINNER * 4);
    float*          pooled = (float*)         alloc((size_t)BATCH_N * DMODEL * 4);

    // Prep
    cast_init<<<(MROWS * DMODEL / 4) / 256, 256, 0, stream>>>(
        x_in, xb, pooled, MROWS * DMODEL / 4);
    transpose_cast<<<dim3(2048 / 32, 512 / 32, NBLK), 256, 0, stream>>>(
        in_proj_w, Wit, 512, 2048, (size_t)512 * 2048, (size_t)2048 * 512);
    transpose_cast<<<dim3(512 / 32, 1024 / 32, NBLK), 256, 0, stream>>>(
        out_proj_w, Wot, 1024, 512, (size_t)1024 * 512, (size_t)512 * 1024);
    transpose_cast<<<dim3(2, 1024 / 32, NBLK), 256, 0, stream>>>(
        x_proj_w, Wxt, 1024, DBLW, (size_t)1024 * DBLW, (size_t)DBLW * 1024);
    transpose_cast<<<dim3(1024 / 32, 1, NBLK), 256, 0, stream>>>(
        dt_proj_w, Wdtt, DTRANK, 1024, (size_t)DTRANK * 1024, (size_t)1024 * DTRANK);
    conv_w_transpose<<<(NBLK * DINNER * KCONV + 255) / 256, 256, 0, stream>>>(conv_w, cwt);

    for (int blk = 0; blk < NBLK; ++blk) {
        const unsigned short* Wit_b  = Wit  + (size_t)blk * 2048 * 512;
        const unsigned short* Wot_b  = Wot  + (size_t)blk * 512 * 1024;
        const unsigned short* Wxt_b  = Wxt  + (size_t)blk * DBLW * 1024;
        const unsigned short* Wdtt_b = Wdtt + (size_t)blk * 1024 * DTRANK;
        const float* cwt_b = cwt + (size_t)blk * KCONV * DINNER;
        const float* cb  = conv_b    + (size_t)blk * DINNER;
        const float* bdt = dt_proj_b + (size_t)blk * DINNER;
        const float* Al  = A_log     + (size_t)blk * DINNER * DSTATE;
        const float* Dv  = Dp        + (size_t)blk * DINNER;

        // 1) xz_bf = bf16(xb @ Wit^T)   K=512, 128x128 tiles
        gemm_bf16<512, 128, 0><<<dim3(2048 / 128, MROWS / 128), 256, 0, stream>>>(
            xb, DMODEL, Wit_b, DMODEL, 2 * DINNER, xz_bf, nullptr);
        // 2) ub = bf16(silu(conv(xz_bf lo) + cb)); zeroes dblsum
        conv_silu_kernel<<<(MROWS * 128) / 256, 256, 0, stream>>>(
            xz_bf, cwt_b, cb, ub, dblsum);
        // 3) dblsum += ub @ Wxt^T (split-K grid x8, atomics)
        gemm_xproj<<<dim3(MROWS / 128, NSPLIT), 256, 0, stream>>>(ub, Wxt_b, dblsum);
        // 4) delta = bf16(softplus(dblsum[:, :32] @ Wdtt^T + bdt))
        gemm_dt<<<dim3(DINNER / 256, MROWS / 64), 256, 0, stream>>>(
            dblsum, Wdtt_b, bdt, delta);
        // 5) chunked scan
        {
            dim3 gridA(NC2, BATCH_N);
            scan_chunk_kernel<<<gridA, 256, 0, stream>>>(delta, ub, dblsum, Al, Pbuf, Sbuf);
            scan_combine_kernel<<<dim3(DINNER / 256, DSTATE, BATCH_N), 256, 0, stream>>>(
                Pbuf, Sbuf);
            scan_out_kernel<<<gridA, 256, 0, stream>>>(delta, ub, dblsum, xz_bf, Al, Dv, Pbuf, ybuf);
        }
        // 6) xb += ybuf @ Wot^T (bf16 residual in-place); last block also
        //    accumulates the mean-pool column sums into pooled[]
        if (blk < NBLK - 1)
            gemm_bf16<1024, 64, 2><<<dim3(DMODEL / 64, MROWS / 128), 256, 0, stream>>>(
                ybuf, DINNER, Wot_b, DINNER, DMODEL, xb, nullptr);
        else
            gemm_bf16<1024, 64, 3><<<dim3(DMODEL / 64, MROWS / 128), 256, 0, stream>>>(
                ybuf, DINNER, Wot_b, DINNER, DMODEL, xb, pooled);
    }

    // classifier on pooled sums
    pool_cls_kernel<<<BATCH_N, DMODEL, 0, stream>>>(pooled, cls_w, cls_b, out);
}